// Round 9
// baseline (123.198 us; speedup 1.0000x reference)
//
#include <hip/hip_runtime.h>

#define B 8
#define N 2048
#define KF 256
#define DF 64
#define LOG2E 1.44269504088896340736f
#define NR 2049   // Rarr rows per batch (position 2048 = "all prefix")

typedef __attribute__((ext_vector_type(8))) short short8;   // 8 bf16 (4 VGPRs)
typedef __attribute__((ext_vector_type(4))) float float4v;  // MFMA C/D frag

__device__ __forceinline__ float fexp2(float x) {
#if __has_builtin(__builtin_amdgcn_exp2f)
    return __builtin_amdgcn_exp2f(x);
#else
    return exp2f(x);
#endif
}
__device__ __forceinline__ float eluf(float x) {
    return x > 0.f ? x : fexp2(x * LOG2E) - 1.0f;
}
// float -> bf16 bits, round-half-up
__device__ __forceinline__ short bf16r(float x) {
    unsigned u = __float_as_uint(x);
    return (short)((u + 0x8000u) >> 16);
}
// monotone float -> sortable uint key (order-preserving for all finite values)
__device__ __forceinline__ unsigned sortkey(float x) {
    unsigned u = __float_as_uint(x);
    return u ^ (((unsigned)((int)u >> 31)) | 0x80000000u);
}
// inverse of sortkey (exact bijection)
__device__ __forceinline__ float invkey(unsigned k) {
    unsigned u = (k & 0x80000000u) ? (k ^ 0x80000000u) : ~k;
    return __uint_as_float(u);
}
#define DOT4(c, u, p) \
    p = fmaf(c.x, u.x, fmaf(c.y, u.y, fmaf(c.z, u.z, fmaf(c.w, u.w, p))));

// ---- A: Wh = h@W via MFMA + fused f1/f2 + fused W-prep. R2/R7-pristine
// (verified). ----
__global__ __launch_bounds__(256) void k_wh(const float* __restrict__ h,
                                            const float* __restrict__ W,
                                            const float* __restrict__ a,
                                            float* __restrict__ Wh,
                                            float* __restrict__ f1,
                                            float* __restrict__ f2) {
    __shared__ __align__(16) unsigned char smem[34816];  // phase union
    short* lwt  = (short*)smem;               // A: [64 n][256 k] bf16 W^T (32 KB)
    float* lv   = (float*)(smem + 32768);     // A: [2][256] v1,v2 (2 KB)
    float* lred = (float*)smem;               // B: [4 wv][16*66] (16.9 KB)
    float* lp   = (float*)(smem + 16896);     // B: [2][4][16]

    int t = threadIdx.x;
    int wv = t >> 6, lane = t & 63;
    int n15 = lane & 15, q = lane >> 4;
    int bx = blockIdx.x;

    // issue tile-0 h loads early (independent of W staging)
    const float* hr = h + ((long)bx * 32 + n15) * KF + wv * 64 + q * 8;
    float4 c0 = *(const float4*)(hr);
    float4 c1 = *(const float4*)(hr + 4);
    float4 c2 = *(const float4*)(hr + 32);
    float4 c3 = *(const float4*)(hr + 36);

    // ---- in-block W prep: thread t owns W row k=t ----
    {
        const float4* wr4 = (const float4*)(W + t * DF);
        float s1 = 0.f, s2 = 0.f;
        #pragma unroll
        for (int c = 0; c < 16; c++) {
            float4 w4 = wr4[c];
            float4 a1v = *(const float4*)(a + 4 * c);        // uniform -> s_load
            float4 a2v = *(const float4*)(a + DF + 4 * c);
            lwt[(4 * c + 0) * 256 + t] = bf16r(w4.x);        // 2-way write: free
            lwt[(4 * c + 1) * 256 + t] = bf16r(w4.y);
            lwt[(4 * c + 2) * 256 + t] = bf16r(w4.z);
            lwt[(4 * c + 3) * 256 + t] = bf16r(w4.w);
            s1 = fmaf(w4.x, a1v.x, fmaf(w4.y, a1v.y, fmaf(w4.z, a1v.z, fmaf(w4.w, a1v.w, s1))));
            s2 = fmaf(w4.x, a2v.x, fmaf(w4.y, a2v.y, fmaf(w4.z, a2v.z, fmaf(w4.w, a2v.w, s2))));
        }
        lv[t] = s1;
        lv[256 + t] = s2;
    }
    __syncthreads();

    // hoist loop-invariant B-frags + v12 (one-time LDS reads)
    const short* bq = lwt + n15 * 256 + wv * 64 + q * 8;
    short8 s0b0 = *(const short8*)(bq);
    short8 s0b1 = *(const short8*)(bq + 16 * 256);
    short8 s0b2 = *(const short8*)(bq + 32 * 256);
    short8 s0b3 = *(const short8*)(bq + 48 * 256);
    short8 s1b0 = *(const short8*)(bq + 32);
    short8 s1b1 = *(const short8*)(bq + 16 * 256 + 32);
    short8 s1b2 = *(const short8*)(bq + 32 * 256 + 32);
    short8 s1b3 = *(const short8*)(bq + 48 * 256 + 32);
    const float* vv = lv + wv * 64 + q * 8;
    float4 u00 = *(const float4*)(vv);
    float4 u01 = *(const float4*)(vv + 4);
    float4 u10 = *(const float4*)(vv + 32);
    float4 u11 = *(const float4*)(vv + 36);
    float4 x00 = *(const float4*)(vv + 256);
    float4 x01 = *(const float4*)(vv + 256 + 4);
    float4 x10 = *(const float4*)(vv + 256 + 32);
    float4 x11 = *(const float4*)(vv + 256 + 36);
    __syncthreads();   // lwt/lv dead; lred region reusable

    #pragma unroll
    for (int rt = 0; rt < 2; rt++) {
        float4 m0, m1, m2, m3;
        if (rt < 1) {                         // prefetch next 16-row tile
            const float* hn = hr + 16 * KF;
            m0 = *(const float4*)(hn);
            m1 = *(const float4*)(hn + 4);
            m2 = *(const float4*)(hn + 32);
            m3 = *(const float4*)(hn + 36);
        }
        float p1 = 0.f, p2 = 0.f;
        DOT4(c0, u00, p1) DOT4(c1, u01, p1) DOT4(c2, u10, p1) DOT4(c3, u11, p1)
        DOT4(c0, x00, p2) DOT4(c1, x01, p2) DOT4(c2, x10, p2) DOT4(c3, x11, p2)

        short8 af0 = { bf16r(c0.x), bf16r(c0.y), bf16r(c0.z), bf16r(c0.w),
                       bf16r(c1.x), bf16r(c1.y), bf16r(c1.z), bf16r(c1.w) };
        short8 af1 = { bf16r(c2.x), bf16r(c2.y), bf16r(c2.z), bf16r(c2.w),
                       bf16r(c3.x), bf16r(c3.y), bf16r(c3.z), bf16r(c3.w) };
        float4v acc0 = {0.f, 0.f, 0.f, 0.f}, acc1 = acc0, acc2 = acc0, acc3 = acc0;
        acc0 = __builtin_amdgcn_mfma_f32_16x16x32_bf16(af0, s0b0, acc0, 0, 0, 0);
        acc0 = __builtin_amdgcn_mfma_f32_16x16x32_bf16(af1, s1b0, acc0, 0, 0, 0);
        acc1 = __builtin_amdgcn_mfma_f32_16x16x32_bf16(af0, s0b1, acc1, 0, 0, 0);
        acc1 = __builtin_amdgcn_mfma_f32_16x16x32_bf16(af1, s1b1, acc1, 0, 0, 0);
        acc2 = __builtin_amdgcn_mfma_f32_16x16x32_bf16(af0, s0b2, acc2, 0, 0, 0);
        acc2 = __builtin_amdgcn_mfma_f32_16x16x32_bf16(af1, s1b2, acc2, 0, 0, 0);
        acc3 = __builtin_amdgcn_mfma_f32_16x16x32_bf16(af0, s0b3, acc3, 0, 0, 0);
        acc3 = __builtin_amdgcn_mfma_f32_16x16x32_bf16(af1, s1b3, acc3, 0, 0, 0);

        #define STASH(nb, A)                                                  \
            {                                                                 \
                _Pragma("unroll")                                             \
                for (int r = 0; r < 4; r++)                                   \
                    lred[wv * 1056 + (q * 4 + r) * 66 + nb * 16 + n15] = A[r]; \
            }
        STASH(0, acc0) STASH(1, acc1) STASH(2, acc2) STASH(3, acc3)
        #undef STASH
        p1 += __shfl_xor(p1, 16, 64); p1 += __shfl_xor(p1, 32, 64);
        p2 += __shfl_xor(p2, 16, 64); p2 += __shfl_xor(p2, 32, 64);
        if (q == 0) { lp[wv * 16 + n15] = p1; lp[64 + wv * 16 + n15] = p2; }
        __syncthreads();

        long i0 = (long)bx * 32 + rt * 16;
        int d = t & 63, ig = t >> 6;
        int bb = (int)(i0 >> 11);
        int il = (int)(i0 & (N - 1));
        float s0 = 0.f, s1 = 0.f, s2 = 0.f, s3 = 0.f;
        #pragma unroll
        for (int w = 0; w < 4; w++) {
            const float* lr = lred + w * 1056 + (ig * 4) * 66 + d;
            s0 += lr[0]; s1 += lr[66]; s2 += lr[132]; s3 += lr[198];
        }
        float* wp = Wh + ((long)bb * N + il + ig * 4) * DF + d;
        wp[0]      = s0;
        wp[DF]     = s1;
        wp[2 * DF] = s2;
        wp[3 * DF] = s3;

        if (t < 16) {
            f1[i0 + t] = lp[t] + lp[16 + t] + lp[32 + t] + lp[48 + t];
        } else if (t < 32) {
            int tt = t + 48;   // 64 + (t-16)
            f2[i0 + t - 16] = lp[tt] + lp[16 + tt] + lp[32 + tt] + lp[48 + tt];
        }
        __syncthreads();
        c0 = m0; c1 = m1; c2 = m2; c3 = m3;
    }
}

// ---- B: SORT + PREFIX + BINARY SEARCH (R8 design; LDS cut 67.6->51.2 KB
// by recomputing exp2 from sorted keys instead of storing E1v/E1sv — exp2
// is 1 VALU op, keys are exact via invkey bijection). One block per batch,
// 1024 thr. Composite (key<<32|idx) uint64 bitonic sorts give exact
// tie-broken permutations; two-level parallel scan (8-elem segs +
// Hillis-Steele over 256); per sorted-f2 position ONE 11-step binary search
// yields den AND Rarr simultaneously. ----
__global__ __launch_bounds__(1024) void k_sort(const float* __restrict__ f1,
                                               const float* __restrict__ f2,
                                               int* __restrict__ si,
                                               float* __restrict__ gA,
                                               float* __restrict__ gsA,
                                               int* __restrict__ s1i,
                                               float2* __restrict__ e1pk,
                                               int* __restrict__ Rarr) {
    __shared__ unsigned long long A1[2048];   // (key(f1)<<32)|idx, asc (16 KB)
    __shared__ unsigned long long A2[2048];   // (key(f2)<<32)|idx, asc (16 KB)
    __shared__ float PS1[2049], PS1s[2049];   // exclusive prefixes (16.4 KB)
    __shared__ float seg1[256], seg1s[256];   // seg sums -> inclusive scan

    int t = threadIdx.x;
    int b = blockIdx.x;
    long bN = (long)b * N;

    #pragma unroll
    for (int r = 0; r < 2; r++) {
        int e = t + r * 1024;
        A1[e] = (((unsigned long long)sortkey(f1[bN + e])) << 32) | (unsigned)e;
        A2[e] = (((unsigned long long)sortkey(f2[bN + e])) << 32) | (unsigned)e;
    }
    __syncthreads();

    // bitonic sort both arrays ascending (same network, shared barriers)
    for (int k = 2; k <= 2048; k <<= 1) {
        for (int j = k >> 1; j > 0; j >>= 1) {
            int i1 = ((t & ~(j - 1)) << 1) | (t & (j - 1));
            int i2 = i1 | j;
            bool up = (i1 & k) == 0;
            unsigned long long a = A1[i1], c = A1[i2];
            if ((a > c) == up) { A1[i1] = c; A1[i2] = a; }
            unsigned long long e = A2[i1], f = A2[i2];
            if ((e > f) == up) { A2[i1] = f; A2[i2] = e; }
            __syncthreads();
        }
    }

    // two-level exclusive prefix of E1 = exp(f1_sorted), E1s = exp(0.2 f1):
    // values recomputed from A1 keys (exact; 1 VALU op each)
    if (t < 256) {
        float s = 0.f;
        #pragma unroll
        for (int x = 0; x < 8; x++) {
            float v = invkey((unsigned)(A1[t * 8 + x] >> 32));
            s += fexp2(v * LOG2E);
        }
        seg1[t] = s;
    } else if (t < 512) {
        int i = t - 256;
        float s = 0.f;
        #pragma unroll
        for (int x = 0; x < 8; x++) {
            float v = invkey((unsigned)(A1[i * 8 + x] >> 32));
            s += fexp2(v * 0.2f * LOG2E);
        }
        seg1s[i] = s;
    }
    __syncthreads();
    // Hillis-Steele inclusive scan of seg1 (thr 0..255) & seg1s (thr 256..511)
    for (int s = 1; s < 256; s <<= 1) {
        float v = 0.f;
        if (t < 256) { if (t >= s) v = seg1[t - s]; }
        else if (t < 512) { int i = t - 256; if (i >= s) v = seg1s[i - s]; }
        __syncthreads();
        if (t < 256) { if (t >= s) seg1[t] += v; }
        else if (t < 512) { int i = t - 256; if (i >= s) seg1s[i] += v; }
        __syncthreads();
    }
    // exclusive PS at every position: seg base + short in-seg walk (<=7)
    #pragma unroll
    for (int r = 0; r < 2; r++) {
        int p = t + r * 1024;
        int sg = p >> 3;
        float b1 = (sg == 0) ? 0.f : seg1[sg - 1];
        float b2 = (sg == 0) ? 0.f : seg1s[sg - 1];
        for (int x = sg * 8; x < p; x++) {
            float v = invkey((unsigned)(A1[x] >> 32));
            b1 += fexp2(v * LOG2E);
            b2 += fexp2(v * 0.2f * LOG2E);
        }
        PS1[p] = b1; PS1s[p] = b2;
    }
    if (t == 0) { PS1[2048] = seg1[255]; PS1s[2048] = seg1s[255]; Rarr[(long)b * NR] = 0; }
    __syncthreads();

    float tot1 = PS1[2048];
    #pragma unroll
    for (int r = 0; r < 2; r++) {
        int p = t + r * 1024;
        // f2-order outputs: den via one binary search; Rarr from the same lo
        unsigned long long a2 = A2[p];
        int jrow = (int)(a2 & 0xFFFFFFFFu);
        float f2v = invkey((unsigned)(a2 >> 32));
        float E2  = fexp2(f2v * LOG2E);
        float E2s = fexp2(f2v * 0.2f * LOG2E);
        unsigned tkey = sortkey(-f2v);
        int lo = 0, hi = 2048;
        while (lo < hi) {
            int mid = (lo + hi) >> 1;
            if ((unsigned)(A1[mid] >> 32) < tkey) lo = mid + 1; else hi = mid;
        }
        float S1  = tot1 - PS1[lo];          // sum_{f1 >= -f2} E1
        float S1s = PS1s[lo];                // sum_{f1 <  -f2} E1s
        float rr = 1.0f / (E2 * S1 + E2s * S1s);
        si [bN + p] = jrow;
        gA [bN + p] = E2 * rr;
        gsA[bN + p] = E2s * rr;
        Rarr[(long)b * NR + p + 1] = N - lo; // #{i: t_i <= p}
        // f1-desc outputs: rank r=p maps to asc position 2047-p
        int asc = 2047 - p;
        unsigned long long a1 = A1[asc];
        float f1v = invkey((unsigned)(a1 >> 32));
        s1i [bN + p] = (int)(a1 & 0xFFFFFFFFu);
        e1pk[bN + p] = make_float2(fexp2(f1v * LOG2E), fexp2(f1v * 0.2f * LOG2E));
    }
}

// ---- C: segment sums (verified R2/R7 body, verbatim). ----
__global__ __launch_bounds__(256) void k_seg(const float* __restrict__ Wh,
                                             const int* __restrict__ si,
                                             const float* __restrict__ gA,
                                             const float* __restrict__ gsA,
                                             float* __restrict__ segG,
                                             float* __restrict__ segGs) {
    int t = threadIdx.x;
    int d = t & 63, sq = t >> 6;
    int seg = blockIdx.x * 4 + sq, b = blockIdx.y;
    const int*   sib = si  + (long)b * N;
    const float* ga  = gA  + (long)b * N;
    const float* gsa = gsA + (long)b * N;
    const float* whb = Wh + (((long)b) << 11) * DF;
    float sg = 0.f, sgs = 0.f;
    #pragma unroll 8
    for (int x = 0; x < 32; x++) {
        int p = seg * 32 + x;
        int r = sib[p];
        float wv = whb[r * DF + d];
        sg  = fmaf(ga[p],  wv, sg);
        sgs = fmaf(gsa[p], wv, sgs);
    }
    segG [(b * 64 + seg) * DF + d] = sg;
    segGs[(b * 64 + seg) * DF + d] = sgs;
}

// ---- D: table walk + direct output scatter (verified R7 body, verbatim). ----
__global__ __launch_bounds__(256) void k_tabout(const float* __restrict__ Wh,
                                                const int* __restrict__ si,
                                                const float* __restrict__ gA,
                                                const float* __restrict__ gsA,
                                                const float* __restrict__ segG,
                                                const float* __restrict__ segGs,
                                                const int* __restrict__ s1i,
                                                const float2* __restrict__ e1pk,
                                                const int* __restrict__ Rarr,
                                                float* __restrict__ out) {
    __shared__ float lPG[4][64], lPGs[4][64];   // sub-partial seg prefixes
    __shared__ float lTG[4][64];                // sub-partial seg totals
    __shared__ float wG[4][64],  wGs[4][64];    // within-seg sub sums
    int t = threadIdx.x;
    int d = t & 63, sub = t >> 6;
    int seg = blockIdx.x, b = blockIdx.y;

    const float* sgb  = segG  + (b * 64) * DF + d;
    const float* sgsb = segGs + (b * 64) * DF + d;
    float pg = 0.f, pgs = 0.f, tg = 0.f;
    #pragma unroll
    for (int k = 0; k < 16; k++) {
        int s = sub * 16 + k;
        float vg = sgb[s * DF], vgs = sgsb[s * DF];
        tg += vg;
        if (s < seg) { pg += vg; pgs += vgs; }
    }
    lPG[sub][d] = pg; lPGs[sub][d] = pgs;
    lTG[sub][d] = tg;

    int p0 = seg * 32 + sub * 8;
    const int*   sib = si  + (long)b * N;
    const float* ga  = gA  + (long)b * N;
    const float* gsa = gsA + (long)b * N;
    const float* whb = Wh + (((long)b) << 11) * DF;
    float rows[8], gv[8], gsv[8];
    float sg = 0.f, sgs = 0.f;
    #pragma unroll
    for (int x = 0; x < 8; x++) {
        int p = p0 + x;
        int r = sib[p];
        float wv = whb[r * DF + d];
        rows[x] = wv; gv[x] = ga[p]; gsv[x] = gsa[p];
        sg  = fmaf(gv[x],  wv, sg);
        sgs = fmaf(gsv[x], wv, sgs);
    }
    wG[sub][d] = sg; wGs[sub][d] = sgs;
    __syncthreads();

    float totG   = lTG[0][d] + lTG[1][d] + lTG[2][d] + lTG[3][d];
    float baseG  = lPG[0][d] + lPG[1][d] + lPG[2][d] + lPG[3][d];
    float baseGs = lPGs[0][d] + lPGs[1][d] + lPGs[2][d] + lPGs[3][d];
    #pragma unroll
    for (int k = 0; k < 3; k++) {
        if (k < sub) { baseG += wG[k][d]; baseGs += wGs[k][d]; }
    }

    const int*    Ra = Rarr + (long)b * NR;
    const int*    s1b = s1i + (long)b * N;
    const float2* e1b = e1pk + (long)b * N;
    float* ob = out + ((long)b * N) * DF + d;

    float rg = baseG, rgs = baseGs;
    #pragma unroll
    for (int x = 0; x < 8; x++) {
        int p = p0 + x;
        float ss = totG - rg;                    // SSg[p]  (suffix incl. p)
        float ps = rgs;                          // PSgs[p] (excl. prefix)
        int r0 = __builtin_amdgcn_readfirstlane(Ra[p]);
        int r1 = __builtin_amdgcn_readfirstlane(Ra[p + 1]);
        for (int rr = r0; rr < r1; rr++) {       // wave-uniform, avg 1 iter
            int row = s1b[rr];
            float2 ee = e1b[rr];
            ob[(long)row * DF] = eluf(ee.x * ss + ee.y * ps);
        }
        rg  = fmaf(gv[x],  rows[x], rg);
        rgs = fmaf(gsv[x], rows[x], rgs);
    }
    if (seg == 63 && sub == 3) {                 // position 2048: pure prefix
        float ps = rgs;
        int r0 = __builtin_amdgcn_readfirstlane(Ra[2048]);
        for (int rr = r0; rr < N; rr++) {
            int row = s1b[rr];
            float2 ee = e1b[rr];
            ob[(long)row * DF] = eluf(ee.y * ps);
        }
    }
}

extern "C" void kernel_launch(void* const* d_in, const int* in_sizes, int n_in,
                              void* d_out, int out_size, void* d_ws, size_t ws_size,
                              hipStream_t stream) {
    const float* h = (const float*)d_in[0];
    const float* W = (const float*)d_in[1];
    const float* a = (const float*)d_in[2];
    float* out = (float*)d_out;

    char* ws = (char*)d_ws;
    const size_t NB = (size_t)B * N;          // 16384 rows
    size_t off = 0;
    float*  Wh    = (float*) (ws + off); off += NB * DF * sizeof(float);   // 4 MB
    float*  f1    = (float*) (ws + off); off += NB * sizeof(float);
    float*  f2    = (float*) (ws + off); off += NB * sizeof(float);
    float*  gA    = (float*) (ws + off); off += NB * sizeof(float);
    float*  gsA   = (float*) (ws + off); off += NB * sizeof(float);
    float2* e1pk  = (float2*)(ws + off); off += NB * sizeof(float2);       // 128 KB
    int*    si    = (int*)   (ws + off); off += NB * sizeof(int);
    int*    s1i   = (int*)   (ws + off); off += NB * sizeof(int);
    int*    Rarr  = (int*)   (ws + off); off += (size_t)B * NR * sizeof(int); // 65.6 KB
    float*  segG  = (float*) (ws + off); off += (size_t)B * 64 * DF * sizeof(float); // 128 KB
    float*  segGs = (float*) (ws + off); off += (size_t)B * 64 * DF * sizeof(float);
    (void)off; (void)ws_size;

    k_wh    <<<NB / 32, 256, 0, stream>>>(h, W, a, Wh, f1, f2);
    k_sort  <<<dim3(B), 1024, 0, stream>>>(f1, f2, si, gA, gsA, s1i, e1pk, Rarr);
    k_seg   <<<dim3(16, B), 256, 0, stream>>>(Wh, si, gA, gsA, segG, segGs);
    k_tabout<<<dim3(64, B), 256, 0, stream>>>(Wh, si, gA, gsA, segG, segGs,
                                              s1i, e1pk, Rarr, out);
}

// Round 10
// 116.699 us; speedup vs baseline: 1.0557x; 1.0557x over previous
//
#include <hip/hip_runtime.h>

#define B 8
#define N 2048
#define KF 256
#define DF 64
#define LOG2E 1.44269504088896340736f
#define NR 2049   // Rarr rows per batch (position 2048 = "all prefix")

typedef __attribute__((ext_vector_type(8))) short short8;   // 8 bf16 (4 VGPRs)
typedef __attribute__((ext_vector_type(4))) float float4v;  // MFMA C/D frag

__device__ __forceinline__ float fexp2(float x) {
#if __has_builtin(__builtin_amdgcn_exp2f)
    return __builtin_amdgcn_exp2f(x);
#else
    return exp2f(x);
#endif
}
__device__ __forceinline__ float eluf(float x) {
    return x > 0.f ? x : fexp2(x * LOG2E) - 1.0f;
}
// float -> bf16 bits, round-half-up
__device__ __forceinline__ short bf16r(float x) {
    unsigned u = __float_as_uint(x);
    return (short)((u + 0x8000u) >> 16);
}
// monotone float -> sortable uint key (order-preserving for all finite values)
__device__ __forceinline__ unsigned sortkey(float x) {
    unsigned u = __float_as_uint(x);
    return u ^ (((unsigned)((int)u >> 31)) | 0x80000000u);
}
#define DOT4(c, u, p) \
    p = fmaf(c.x, u.x, fmaf(c.y, u.y, fmaf(c.z, u.z, fmaf(c.w, u.w, p))));

// ---- A: Wh = h@W via MFMA + fused f1/f2 + fused W-prep. R2-pristine
// (verified). ----
__global__ __launch_bounds__(256) void k_wh(const float* __restrict__ h,
                                            const float* __restrict__ W,
                                            const float* __restrict__ a,
                                            float* __restrict__ Wh,
                                            float* __restrict__ f1,
                                            float* __restrict__ f2) {
    __shared__ __align__(16) unsigned char smem[34816];  // phase union
    short* lwt  = (short*)smem;               // A: [64 n][256 k] bf16 W^T (32 KB)
    float* lv   = (float*)(smem + 32768);     // A: [2][256] v1,v2 (2 KB)
    float* lred = (float*)smem;               // B: [4 wv][16*66] (16.9 KB)
    float* lp   = (float*)(smem + 16896);     // B: [2][4][16]

    int t = threadIdx.x;
    int wv = t >> 6, lane = t & 63;
    int n15 = lane & 15, q = lane >> 4;
    int bx = blockIdx.x;

    // issue tile-0 h loads early (independent of W staging)
    const float* hr = h + ((long)bx * 32 + n15) * KF + wv * 64 + q * 8;
    float4 c0 = *(const float4*)(hr);
    float4 c1 = *(const float4*)(hr + 4);
    float4 c2 = *(const float4*)(hr + 32);
    float4 c3 = *(const float4*)(hr + 36);

    // ---- in-block W prep: thread t owns W row k=t ----
    {
        const float4* wr4 = (const float4*)(W + t * DF);
        float s1 = 0.f, s2 = 0.f;
        #pragma unroll
        for (int c = 0; c < 16; c++) {
            float4 w4 = wr4[c];
            float4 a1v = *(const float4*)(a + 4 * c);        // uniform -> s_load
            float4 a2v = *(const float4*)(a + DF + 4 * c);
            lwt[(4 * c + 0) * 256 + t] = bf16r(w4.x);        // 2-way write: free
            lwt[(4 * c + 1) * 256 + t] = bf16r(w4.y);
            lwt[(4 * c + 2) * 256 + t] = bf16r(w4.z);
            lwt[(4 * c + 3) * 256 + t] = bf16r(w4.w);
            s1 = fmaf(w4.x, a1v.x, fmaf(w4.y, a1v.y, fmaf(w4.z, a1v.z, fmaf(w4.w, a1v.w, s1))));
            s2 = fmaf(w4.x, a2v.x, fmaf(w4.y, a2v.y, fmaf(w4.z, a2v.z, fmaf(w4.w, a2v.w, s2))));
        }
        lv[t] = s1;
        lv[256 + t] = s2;
    }
    __syncthreads();

    // hoist loop-invariant B-frags + v12 (one-time LDS reads)
    const short* bq = lwt + n15 * 256 + wv * 64 + q * 8;
    short8 s0b0 = *(const short8*)(bq);
    short8 s0b1 = *(const short8*)(bq + 16 * 256);
    short8 s0b2 = *(const short8*)(bq + 32 * 256);
    short8 s0b3 = *(const short8*)(bq + 48 * 256);
    short8 s1b0 = *(const short8*)(bq + 32);
    short8 s1b1 = *(const short8*)(bq + 16 * 256 + 32);
    short8 s1b2 = *(const short8*)(bq + 32 * 256 + 32);
    short8 s1b3 = *(const short8*)(bq + 48 * 256 + 32);
    const float* vv = lv + wv * 64 + q * 8;
    float4 u00 = *(const float4*)(vv);
    float4 u01 = *(const float4*)(vv + 4);
    float4 u10 = *(const float4*)(vv + 32);
    float4 u11 = *(const float4*)(vv + 36);
    float4 x00 = *(const float4*)(vv + 256);
    float4 x01 = *(const float4*)(vv + 256 + 4);
    float4 x10 = *(const float4*)(vv + 256 + 32);
    float4 x11 = *(const float4*)(vv + 256 + 36);
    __syncthreads();   // lwt/lv dead; lred region reusable

    #pragma unroll
    for (int rt = 0; rt < 2; rt++) {
        float4 m0, m1, m2, m3;
        if (rt < 1) {                         // prefetch next 16-row tile
            const float* hn = hr + 16 * KF;
            m0 = *(const float4*)(hn);
            m1 = *(const float4*)(hn + 4);
            m2 = *(const float4*)(hn + 32);
            m3 = *(const float4*)(hn + 36);
        }
        float p1 = 0.f, p2 = 0.f;
        DOT4(c0, u00, p1) DOT4(c1, u01, p1) DOT4(c2, u10, p1) DOT4(c3, u11, p1)
        DOT4(c0, x00, p2) DOT4(c1, x01, p2) DOT4(c2, x10, p2) DOT4(c3, x11, p2)

        short8 af0 = { bf16r(c0.x), bf16r(c0.y), bf16r(c0.z), bf16r(c0.w),
                       bf16r(c1.x), bf16r(c1.y), bf16r(c1.z), bf16r(c1.w) };
        short8 af1 = { bf16r(c2.x), bf16r(c2.y), bf16r(c2.z), bf16r(c2.w),
                       bf16r(c3.x), bf16r(c3.y), bf16r(c3.z), bf16r(c3.w) };
        float4v acc0 = {0.f, 0.f, 0.f, 0.f}, acc1 = acc0, acc2 = acc0, acc3 = acc0;
        acc0 = __builtin_amdgcn_mfma_f32_16x16x32_bf16(af0, s0b0, acc0, 0, 0, 0);
        acc0 = __builtin_amdgcn_mfma_f32_16x16x32_bf16(af1, s1b0, acc0, 0, 0, 0);
        acc1 = __builtin_amdgcn_mfma_f32_16x16x32_bf16(af0, s0b1, acc1, 0, 0, 0);
        acc1 = __builtin_amdgcn_mfma_f32_16x16x32_bf16(af1, s1b1, acc1, 0, 0, 0);
        acc2 = __builtin_amdgcn_mfma_f32_16x16x32_bf16(af0, s0b2, acc2, 0, 0, 0);
        acc2 = __builtin_amdgcn_mfma_f32_16x16x32_bf16(af1, s1b2, acc2, 0, 0, 0);
        acc3 = __builtin_amdgcn_mfma_f32_16x16x32_bf16(af0, s0b3, acc3, 0, 0, 0);
        acc3 = __builtin_amdgcn_mfma_f32_16x16x32_bf16(af1, s1b3, acc3, 0, 0, 0);

        #define STASH(nb, A)                                                  \
            {                                                                 \
                _Pragma("unroll")                                             \
                for (int r = 0; r < 4; r++)                                   \
                    lred[wv * 1056 + (q * 4 + r) * 66 + nb * 16 + n15] = A[r]; \
            }
        STASH(0, acc0) STASH(1, acc1) STASH(2, acc2) STASH(3, acc3)
        #undef STASH
        p1 += __shfl_xor(p1, 16, 64); p1 += __shfl_xor(p1, 32, 64);
        p2 += __shfl_xor(p2, 16, 64); p2 += __shfl_xor(p2, 32, 64);
        if (q == 0) { lp[wv * 16 + n15] = p1; lp[64 + wv * 16 + n15] = p2; }
        __syncthreads();

        long i0 = (long)bx * 32 + rt * 16;
        int d = t & 63, ig = t >> 6;
        int bb = (int)(i0 >> 11);
        int il = (int)(i0 & (N - 1));
        float s0 = 0.f, s1 = 0.f, s2 = 0.f, s3 = 0.f;
        #pragma unroll
        for (int w = 0; w < 4; w++) {
            const float* lr = lred + w * 1056 + (ig * 4) * 66 + d;
            s0 += lr[0]; s1 += lr[66]; s2 += lr[132]; s3 += lr[198];
        }
        float* wp = Wh + ((long)bb * N + il + ig * 4) * DF + d;
        wp[0]      = s0;
        wp[DF]     = s1;
        wp[2 * DF] = s2;
        wp[3 * DF] = s3;

        if (t < 16) {
            f1[i0 + t] = lp[t] + lp[16 + t] + lp[32 + t] + lp[48 + t];
        } else if (t < 32) {
            int tt = t + 48;   // 64 + (t-16)
            f2[i0 + t - 16] = lp[tt] + lp[16 + tt] + lp[32 + tt] + lp[48 + tt];
        }
        __syncthreads();
        c0 = m0; c1 = m1; c2 = m2; c3 = m3;
    }
}

// ---- B: brute-force ranks + denominators, 2-j register blocking. R2's
// verified compare semantics; each thread owns rows base+jl and base+64+jl,
// so every {qv,u2} broadcast LDS read is amortized over 2 rows (the R2
// version was LDS-issue-bound at 2 reads / 12 VALU; now 2 / 24).
// Outputs: tIdx (threshold counts), si/gA/gsA scattered to f2-rank order. ----
__global__ __launch_bounds__(512) void k_rank(const float* __restrict__ f1,
                                              const float* __restrict__ f2,
                                              int* __restrict__ tIdx,
                                              int* __restrict__ si,
                                              float* __restrict__ gA,
                                              float* __restrict__ gsA) {
    __shared__ __align__(16) float4 qv[2048];   // {f1, E1, E1s, f2} (32 KB)
    __shared__ unsigned u2[2048];               // sortable bits of f2 (8 KB)
    __shared__ float rS1[8][128], rS1s[8][128]; // (8 KB)
    __shared__ int   rC2[8][128], rC3[8][128];  // (8 KB)

    int t = threadIdx.x;
    int b = blockIdx.y;
    int base = blockIdx.x * 128;
    long bN = (long)b * N;

    #pragma unroll
    for (int r = 0; r < 4; r++) {
        int idx = t + r * 512;
        float v1 = f1[bN + idx], v2 = f2[bN + idx];
        qv[idx] = make_float4(v1, fexp2(v1 * LOG2E), fexp2(v1 * 0.2f * LOG2E), v2);
        u2[idx] = sortkey(v2);
    }
    __syncthreads();

    int jl = t & 63, qt = t >> 6;       // qt wave-uniform (8 p-chunks)
    int ja = base + jl, jb = base + 64 + jl;
    float4 qja = qv[ja], qjb = qv[jb];
    unsigned uja = u2[ja], ujb = u2[jb];
    float negf2a = -qja.w, negf1a = -qja.x;
    float negf2b = -qjb.w, negf1b = -qjb.x;
    int c2a = 0, c3a = 0, c2b = 0, c3b = 0;
    float S1a = 0.f, S1sa = 0.f, S1b = 0.f, S1sb = 0.f;
    int p0 = qt * 256;
    #pragma unroll 4
    for (int p = p0; p < p0 + 256; p++) {
        float4 qa = qv[p];              // broadcast b128 (shared by 2 rows)
        unsigned up = u2[p];            // broadcast b32
        c2a += (up < uja || (up == uja && p < ja)) ? 1 : 0;
        c2b += (up < ujb || (up == ujb && p < jb)) ? 1 : 0;
        bool ca = qa.x < negf2a;        // f1_p < -f2_ja
        bool cb = qa.x < negf2b;
        S1a  += ca ? 0.f : qa.y;   S1sa += ca ? qa.z : 0.f;
        S1b  += cb ? 0.f : qa.y;   S1sb += cb ? qa.z : 0.f;
        c3a += (qa.w < negf1a) ? 1 : 0;
        c3b += (qa.w < negf1b) ? 1 : 0;
    }
    rC2[qt][jl] = c2a;  rC2[qt][64 + jl] = c2b;
    rC3[qt][jl] = c3a;  rC3[qt][64 + jl] = c3b;
    rS1[qt][jl] = S1a;  rS1[qt][64 + jl] = S1b;
    rS1s[qt][jl] = S1sa; rS1s[qt][64 + jl] = S1sb;
    __syncthreads();

    if (t < 128) {
        int j2 = base + t;
        float4 qj2 = qv[j2];
        int rank = 0, ti = 0;
        float s1 = 0.f, s1s = 0.f;
        #pragma unroll
        for (int k = 0; k < 8; k++) {
            rank += rC2[k][t]; ti += rC3[k][t];
            s1 += rS1[k][t];   s1s += rS1s[k][t];
        }
        float E2  = fexp2(qj2.w * LOG2E);
        float E2s = fexp2(qj2.w * 0.2f * LOG2E);
        float rr = 1.0f / (E2 * s1 + E2s * s1s);
        tIdx[bN + j2] = ti;
        si [bN + rank] = j2;            // scatter: f2-sorted order
        gA [bN + rank] = E2 * rr;
        gsA[bN + rank] = E2s * rr;
    }
}

// ---- C: grid (17,B). x<16: segment sums (verified R2 body, verbatim).
// x==16: bucket build — histogram of tIdx over 2049 buckets, 2-level scan
// -> Rarr (exclusive counts #{i: t_i < p}), then atomic-slot scatter of
// rows into their bucket ranges -> s1i + e1pk {E1,E1s}. Within-bucket order
// is arbitrary (all rows of a bucket read identical table values). ----
__global__ __launch_bounds__(256) void k_segbkt(const float* __restrict__ Wh,
                                                const int* __restrict__ si,
                                                const float* __restrict__ gA,
                                                const float* __restrict__ gsA,
                                                const float* __restrict__ f1,
                                                const int* __restrict__ tIdx,
                                                float* __restrict__ segG,
                                                float* __restrict__ segGs,
                                                int* __restrict__ s1i,
                                                float2* __restrict__ e1pk,
                                                int* __restrict__ Rarr) {
    __shared__ int hist[2049];
    __shared__ int Rl[2049];
    __shared__ int part[256];
    int t = threadIdx.x;
    int b = blockIdx.y;
    int x = blockIdx.x;
    long bN = (long)b * N;

    if (x < 16) {                       // ---- seg-sum body (verified) ----
        int d = t & 63, sq = t >> 6;
        int seg = x * 4 + sq;
        const int*   sib = si  + bN;
        const float* ga  = gA  + bN;
        const float* gsa = gsA + bN;
        const float* whb = Wh + (((long)b) << 11) * DF;
        float sg = 0.f, sgs = 0.f;
        #pragma unroll 8
        for (int k = 0; k < 32; k++) {
            int p = seg * 32 + k;
            int r = sib[p];
            float wv = whb[r * DF + d];
            sg  = fmaf(ga[p],  wv, sg);
            sgs = fmaf(gsa[p], wv, sgs);
        }
        segG [(b * 64 + seg) * DF + d] = sg;
        segGs[(b * 64 + seg) * DF + d] = sgs;
        return;                         // block-uniform exit (no barriers used)
    }

    // ---- bucket build (x == 16) ----
    for (int i = t; i < 2049; i += 256) hist[i] = 0;
    __syncthreads();
    int tis[8];
    #pragma unroll
    for (int r = 0; r < 8; r++) {
        int i = t + r * 256;
        int ti = tIdx[bN + i];
        tis[r] = ti;
        atomicAdd(&hist[ti], 1);
    }
    __syncthreads();
    int s = 0;
    #pragma unroll
    for (int k = 0; k < 8; k++) s += hist[t * 8 + k];
    part[t] = s;
    __syncthreads();
    for (int st = 1; st < 256; st <<= 1) {      // Hillis-Steele inclusive scan
        int v = (t >= st) ? part[t - st] : 0;
        __syncthreads();
        part[t] += v;
        __syncthreads();
    }
    int run = (t == 0) ? 0 : part[t - 1];       // exclusive base for 8-bucket walk
    #pragma unroll
    for (int k = 0; k < 8; k++) {
        int p = t * 8 + k;
        Rl[p] = run;
        Rarr[(long)b * NR + p] = run;
        run += hist[p];
    }
    if (t == 255) { Rl[2048] = run; Rarr[(long)b * NR + 2048] = run; }
    __syncthreads();
    #pragma unroll
    for (int r = 0; r < 8; r++) {
        int i = t + r * 256;
        int slot = atomicAdd(&Rl[tis[r]], 1);   // unique slot in bucket range
        s1i[bN + slot] = i;
        float v = f1[bN + i];
        e1pk[bN + slot] = make_float2(fexp2(v * LOG2E), fexp2(v * 0.2f * LOG2E));
    }
}

// ---- D: table walk + direct output scatter (verified R9 body, verbatim). ----
__global__ __launch_bounds__(256) void k_tabout(const float* __restrict__ Wh,
                                                const int* __restrict__ si,
                                                const float* __restrict__ gA,
                                                const float* __restrict__ gsA,
                                                const float* __restrict__ segG,
                                                const float* __restrict__ segGs,
                                                const int* __restrict__ s1i,
                                                const float2* __restrict__ e1pk,
                                                const int* __restrict__ Rarr,
                                                float* __restrict__ out) {
    __shared__ float lPG[4][64], lPGs[4][64];   // sub-partial seg prefixes
    __shared__ float lTG[4][64];                // sub-partial seg totals
    __shared__ float wG[4][64],  wGs[4][64];    // within-seg sub sums
    int t = threadIdx.x;
    int d = t & 63, sub = t >> 6;
    int seg = blockIdx.x, b = blockIdx.y;

    const float* sgb  = segG  + (b * 64) * DF + d;
    const float* sgsb = segGs + (b * 64) * DF + d;
    float pg = 0.f, pgs = 0.f, tg = 0.f;
    #pragma unroll
    for (int k = 0; k < 16; k++) {
        int s = sub * 16 + k;
        float vg = sgb[s * DF], vgs = sgsb[s * DF];
        tg += vg;
        if (s < seg) { pg += vg; pgs += vgs; }
    }
    lPG[sub][d] = pg; lPGs[sub][d] = pgs;
    lTG[sub][d] = tg;

    int p0 = seg * 32 + sub * 8;
    const int*   sib = si  + (long)b * N;
    const float* ga  = gA  + (long)b * N;
    const float* gsa = gsA + (long)b * N;
    const float* whb = Wh + (((long)b) << 11) * DF;
    float rows[8], gv[8], gsv[8];
    float sg = 0.f, sgs = 0.f;
    #pragma unroll
    for (int x = 0; x < 8; x++) {
        int p = p0 + x;
        int r = sib[p];
        float wv = whb[r * DF + d];
        rows[x] = wv; gv[x] = ga[p]; gsv[x] = gsa[p];
        sg  = fmaf(gv[x],  wv, sg);
        sgs = fmaf(gsv[x], wv, sgs);
    }
    wG[sub][d] = sg; wGs[sub][d] = sgs;
    __syncthreads();

    float totG   = lTG[0][d] + lTG[1][d] + lTG[2][d] + lTG[3][d];
    float baseG  = lPG[0][d] + lPG[1][d] + lPG[2][d] + lPG[3][d];
    float baseGs = lPGs[0][d] + lPGs[1][d] + lPGs[2][d] + lPGs[3][d];
    #pragma unroll
    for (int k = 0; k < 3; k++) {
        if (k < sub) { baseG += wG[k][d]; baseGs += wGs[k][d]; }
    }

    const int*    Ra = Rarr + (long)b * NR;
    const int*    s1b = s1i + (long)b * N;
    const float2* e1b = e1pk + (long)b * N;
    float* ob = out + ((long)b * N) * DF + d;

    float rg = baseG, rgs = baseGs;
    #pragma unroll
    for (int x = 0; x < 8; x++) {
        int p = p0 + x;
        float ss = totG - rg;                    // SSg[p]  (suffix incl. p)
        float ps = rgs;                          // PSgs[p] (excl. prefix)
        int r0 = __builtin_amdgcn_readfirstlane(Ra[p]);
        int r1 = __builtin_amdgcn_readfirstlane(Ra[p + 1]);
        for (int rr = r0; rr < r1; rr++) {       // wave-uniform, avg 1 iter
            int row = s1b[rr];
            float2 ee = e1b[rr];
            ob[(long)row * DF] = eluf(ee.x * ss + ee.y * ps);
        }
        rg  = fmaf(gv[x],  rows[x], rg);
        rgs = fmaf(gsv[x], rows[x], rgs);
    }
    if (seg == 63 && sub == 3) {                 // position 2048: pure prefix
        float ps = rgs;
        int r0 = __builtin_amdgcn_readfirstlane(Ra[2048]);
        for (int rr = r0; rr < N; rr++) {
            int row = s1b[rr];
            float2 ee = e1b[rr];
            ob[(long)row * DF] = eluf(ee.y * ps);
        }
    }
}

extern "C" void kernel_launch(void* const* d_in, const int* in_sizes, int n_in,
                              void* d_out, int out_size, void* d_ws, size_t ws_size,
                              hipStream_t stream) {
    const float* h = (const float*)d_in[0];
    const float* W = (const float*)d_in[1];
    const float* a = (const float*)d_in[2];
    float* out = (float*)d_out;

    char* ws = (char*)d_ws;
    const size_t NB = (size_t)B * N;          // 16384 rows
    size_t off = 0;
    float*  Wh    = (float*) (ws + off); off += NB * DF * sizeof(float);   // 4 MB
    float*  f1    = (float*) (ws + off); off += NB * sizeof(float);
    float*  f2    = (float*) (ws + off); off += NB * sizeof(float);
    float*  gA    = (float*) (ws + off); off += NB * sizeof(float);
    float*  gsA   = (float*) (ws + off); off += NB * sizeof(float);
    float2* e1pk  = (float2*)(ws + off); off += NB * sizeof(float2);       // 128 KB
    int*    tIdx  = (int*)   (ws + off); off += NB * sizeof(int);
    int*    si    = (int*)   (ws + off); off += NB * sizeof(int);
    int*    s1i   = (int*)   (ws + off); off += NB * sizeof(int);
    int*    Rarr  = (int*)   (ws + off); off += (size_t)B * NR * sizeof(int); // 65.6 KB
    float*  segG  = (float*) (ws + off); off += (size_t)B * 64 * DF * sizeof(float); // 128 KB
    float*  segGs = (float*) (ws + off); off += (size_t)B * 64 * DF * sizeof(float);
    (void)off; (void)ws_size;

    k_wh    <<<NB / 32, 256, 0, stream>>>(h, W, a, Wh, f1, f2);
    k_rank  <<<dim3(N / 128, B), 512, 0, stream>>>(f1, f2, tIdx, si, gA, gsA);
    k_segbkt<<<dim3(17, B), 256, 0, stream>>>(Wh, si, gA, gsA, f1, tIdx,
                                              segG, segGs, s1i, e1pk, Rarr);
    k_tabout<<<dim3(64, B), 256, 0, stream>>>(Wh, si, gA, gsA, segG, segGs,
                                              s1i, e1pk, Rarr, out);
}